// Round 17
// baseline (647.816 us; speedup 1.0000x reference)
//
#include <hip/hip_runtime.h>

namespace {

constexpr int Bn = 32, Cn = 8, Hn = 512, In = 512;
constexpr size_t HI = (size_t)Hn * In;     // 262144
constexpr float SC = 1.0f / 5000.0f;

using s16x8 = __attribute__((ext_vector_type(8))) short;
using f32x4 = __attribute__((ext_vector_type(4))) float;

__device__ __forceinline__ float actf(float x) {
    return fminf(1.0f, fmaxf(-1.0f, x));   // hardtanh
}

__device__ __forceinline__ unsigned short f2bf(float f) {   // RNE f32->bf16
    unsigned u = __builtin_bit_cast(unsigned, f);
    u += 0x7FFFu + ((u >> 16) & 1u);
    return (unsigned short)(u >> 16);
}
__device__ __forceinline__ float bf2f(unsigned short h) {
    return __builtin_bit_cast(float, (unsigned)h << 16);
}

__device__ __forceinline__ void async16(const void* g, void* l) {
    __builtin_amdgcn_global_load_lds(
        (const __attribute__((address_space(1))) unsigned*)g,
        (__attribute__((address_space(3))) unsigned*)l, 16, 0, 0);
}

// ---------------------------------------------------------------------------
// bf16 MFMA GEMM, r17: BARRIER-FREE wave-private pipeline.
// 128x128 tile, 4 waves; each wave owns a 64x64 output quadrant and stages
// ITS OWN A-half and B-half into a private double-buffered 16KB LDS region
// (2x duplication per half, absorbed by L2 — panels are XCD-localized, r12).
// K-loop per wave: vmcnt(8) [own tile t landed; t+1 stays in flight] ->
// 8 ds_read + 16 MFMA -> lgkmcnt(0) [reads retired] -> stage(t+2).
// NO s_barrier anywhere: waves fully self-paced (removes the 2-barriers x
// 16-steps x 16-slots lockstep cost that survived r13-r16 elimination).
// Coalescing: per async16, 16 rows x 64B segments (same as champion).
// XOR bank-swizzle (r15) re-derived for 64-row tile: store byte
// (lane&3)*16 ^ (((lane>>3)&3)<<4); read kq*16 ^ (((l15>>1)&3)<<4). Same
// involution both sides; conflicts stay 0.
// PCOL/TRI/EPI semantics as before (r12/r15).
// ---------------------------------------------------------------------------
template<int EPI, bool PCOL, bool TRI>
__global__ __launch_bounds__(256, 2) void mfma_gemm(
    const unsigned short* __restrict__ A,
    const unsigned short* __restrict__ Bt,
    const float* __restrict__ bias,
    const float* __restrict__ zrow,
    unsigned short* __restrict__ out0,
    unsigned short* __restrict__ out1,
    float* __restrict__ outf,
    size_t sB, size_t sC)
{
    __shared__ __align__(16) char lds[4][2][8192];   // [wave][buf][A 4KB | B 4KB]

    const int tid  = threadIdx.x;
    const int wid  = tid >> 6, lane = tid & 63;
    const int wr   = wid >> 1, wc = wid & 1;
    const int l15  = lane & 15, kq = lane >> 4;

    const int bid = blockIdx.x;
    const int p = ((bid >> 5) << 3) | (bid & 7);   // panel id (same-XCD group)
    const int q = (bid >> 3) & 3;                  // member within panel group
    const int rt = PCOL ? q : p;                   // A-row tile
    const int ct = PCOL ? (p & 3) : q;             // col tile
    const size_t zb = PCOL ? (size_t)(p >> 2) : 0;

    // wave-local operand bases: A rows rt*128+wr*64.., B rows ct*128+wc*64..
    const char* Aw = (const char*)A + ((size_t)rt * 128 + wr * 64) * 1024;
    const char* Bw = (const char*)(Bt + zb * sB) + ((size_t)ct * 128 + wc * 64) * 1024;

    f32x4 acc[4][4] = {};

    // staging: lane covers row lane>>2 (+16 per instr), byte (lane&3)*16.
    const int srow = lane >> 2;                    // 0..15
    const int csw  = ((lane & 3) * 16) ^ (((lane >> 3) & 3) << 4); // swizzled byte
    char* myl = &lds[wid][0][0];

    auto stage = [&](int buf, int k0b) {
        char* d = myl + buf * 8192;
        const char* Ag = Aw + k0b + csw;
        const char* Bg = Bw + k0b + csw;
        #pragma unroll
        for (int i = 0; i < 4; ++i)
            async16(Ag + (size_t)(srow + 16 * i) * 1024, d + i * 1024 + lane * 16);
        #pragma unroll
        for (int i = 0; i < 4; ++i)
            async16(Bg + (size_t)(srow + 16 * i) * 1024, d + 4096 + i * 1024 + lane * 16);
    };
    auto compute = [&](int buf) {
        const char* pp = myl + buf * 8192;
        s16x8 a[4], b[4];
        const int kx = kq * 16 ^ (((l15 >> 1) & 3) << 4);
        #pragma unroll
        for (int m = 0; m < 4; ++m)
            a[m] = *(const s16x8*)(pp + (size_t)(m * 16 + l15) * 64 + kx);
        #pragma unroll
        for (int n = 0; n < 4; ++n)
            b[n] = *(const s16x8*)(pp + 4096 + (size_t)(n * 16 + l15) * 64 + kx);
        #pragma unroll
        for (int m = 0; m < 4; ++m)
            #pragma unroll
            for (int n = 0; n < 4; ++n)
                acc[m][n] = __builtin_amdgcn_mfma_f32_16x16x32_bf16(a[m], b[n], acc[m][n], 0, 0, 0);
    };

    const int kSteps = TRI ? (rt + 1) * 4 : 16;

    stage(0, 0);
    stage(1, 64);

    #pragma unroll 1
    for (int ks = 0; ks < kSteps; ++ks) {
        if (ks + 1 < kSteps)
            asm volatile("s_waitcnt vmcnt(8)" ::: "memory");   // tile ks landed
        else
            asm volatile("s_waitcnt vmcnt(0)" ::: "memory");
        compute(ks & 1);
        if (ks + 2 < kSteps) {
            asm volatile("s_waitcnt lgkmcnt(0)" ::: "memory"); // own reads retired
            stage(ks & 1, (ks + 2) * 64);
        }
    }

    // ---- epilogue: C/D layout col=lane&15, row=(lane>>4)*4+j ----
    const int cb = ct * 128 + wc * 64 + l15;
    const int rb = rt * 128 + wr * 64 + (kq << 2);
    #pragma unroll
    for (int m = 0; m < 4; ++m) {
        #pragma unroll
        for (int n = 0; n < 4; ++n) {
            const int c = cb + n * 16;
            #pragma unroll
            for (int j = 0; j < 4; ++j) {
                const int r = rb + m * 16 + j;
                float v = acc[m][n][j];
                const size_t idx = zb * sC + (size_t)r * 512 + c;
                if (EPI == 0) {
                    out0[idx] = f2bf(actf(v));
                } else if (EPI == 1) {
                    float tp = actf(v + bias[c]);
                    out0[idx] = f2bf(tp);
                    out1[idx] = f2bf(actf(zrow[r & 511] * tp));
                } else if (EPI == 2) {
                    out0[idx] = f2bf(actf(v + bias[c]));
                } else if (EPI == 3) {
                    out0[idx] = f2bf(fmaxf(v + bias[c], 0.0f));
                } else {
                    outf[idx] = v + bias[c];
                }
            }
        }
    }
}

// comb[b] = bf16( x0[b]/5000 + sum_c tp[b,c] + sum_c tz[b,c] )
__global__ __launch_bounds__(256) void reduce_both(
    const unsigned short* __restrict__ tp,
    const unsigned short* __restrict__ tz,
    const float* __restrict__ x0,
    unsigned short* __restrict__ comb)
{
    size_t idx = (size_t)blockIdx.x * 256 + threadIdx.x;   // float4 slot
    size_t b = idx >> 16;                                  // / (HI/4)
    size_t p = (idx & 65535) * 4;
    float4 xv = *(const float4*)&x0[(b * Cn) * HI + p];
    float s0 = xv.x * SC, s1 = xv.y * SC, s2 = xv.z * SC, s3 = xv.w * SC;
    #pragma unroll
    for (int c = 0; c < Cn; ++c) {
        size_t q = (b * Cn + c) * HI + p;
        ushort4 a = *(const ushort4*)&tp[q];
        ushort4 d = *(const ushort4*)&tz[q];
        s0 += bf2f(a.x) + bf2f(d.x);
        s1 += bf2f(a.y) + bf2f(d.y);
        s2 += bf2f(a.z) + bf2f(d.z);
        s3 += bf2f(a.w) + bf2f(d.w);
    }
    ushort4 o;
    o.x = f2bf(s0); o.y = f2bf(s1); o.z = f2bf(s2); o.w = f2bf(s3);
    *(ushort4*)&comb[b * HI + p] = o;
}

// xst[bc][i][k] = bf16( x[bc][k][i] * act(mask[k][i]) / 5000 )
__global__ __launch_bounds__(256) void transpose_mask(
    const float* __restrict__ x, const float* __restrict__ mask,
    unsigned short* __restrict__ xst)
{
    __shared__ float t[64][65];
    const int bc = blockIdx.z;
    const int i0 = blockIdx.x * 64, k0 = blockIdx.y * 64;
    const int r4 = threadIdx.x >> 6, cc = threadIdx.x & 63;
    const float* xp = x + (size_t)bc * HI;
    #pragma unroll
    for (int it = 0; it < 16; ++it) {
        int kl = it * 4 + r4;
        size_t g = (size_t)(k0 + kl) * In + i0 + cc;
        t[kl][cc] = xp[g] * (actf(mask[g]) * SC);
    }
    __syncthreads();
    unsigned short* op = xst + (size_t)bc * HI;
    #pragma unroll
    for (int it = 0; it < 16; ++it) {
        int il = it * 4 + r4;
        op[(size_t)(i0 + il) * Hn + k0 + cc] = f2bf(t[cc][il]);
    }
}

__global__ __launch_bounds__(256) void prep_wpe_bf(
    const float* __restrict__ Wp, const float* __restrict__ Wpd,
    unsigned short* __restrict__ o)
{
    int idx = blockIdx.x * 256 + threadIdx.x;
    int i = idx >> 9, j = idx & 511;
    o[idx] = f2bf(Wp[idx] + (i == j ? Wpd[i] : 0.0f));
}

__global__ __launch_bounds__(256) void conv_bf(
    const float* __restrict__ s, unsigned short* __restrict__ o)
{
    int idx = blockIdx.x * 256 + threadIdx.x;
    o[idx] = f2bf(s[idx]);
}

__global__ __launch_bounds__(64) void rowsum(
    const float* __restrict__ W, float* __restrict__ zr)
{
    int h = blockIdx.x, l = threadIdx.x;
    float s = 0.0f;
    for (int k = l; k < Hn; k += 64) s += W[h * Hn + k];
    #pragma unroll
    for (int off = 32; off; off >>= 1) s += __shfl_down(s, off, 64);
    if (!l) zr[h] = s;
}

} // namespace

extern "C" void kernel_launch(void* const* d_in, const int* in_sizes, int n_in,
                              void* d_out, int out_size, void* d_ws, size_t ws_size,
                              hipStream_t stream)
{
    const float* input  = (const float*)d_in[0];
    const float* p_mask = (const float*)d_in[1];
    const float* Wp     = (const float*)d_in[2];
    const float* Wpd    = (const float*)d_in[3];
    const float* Wzp    = (const float*)d_in[4];
    const float* plw    = (const float*)d_in[5];
    const float* plb    = (const float*)d_in[6];
    const float* zlw    = (const float*)d_in[7];
    const float* zlb    = (const float*)d_in[8];
    const float* f1w    = (const float*)d_in[9];
    const float* f1b    = (const float*)d_in[10];
    const float* f2w    = (const float*)d_in[11];
    const float* f2b    = (const float*)d_in[12];

    constexpr size_t WB = 512 * 512 * 2;   // one bf16 weight matrix
    char* w = (char*)d_ws;
    auto alloc = [&](size_t bytes) { char* p = w; w += (bytes + 255) & ~255ull; return p; };

    unsigned short* Wpeb  = (unsigned short*)alloc(WB);
    unsigned short* plwb  = (unsigned short*)alloc(WB);
    unsigned short* zlwb  = (unsigned short*)alloc(WB);
    unsigned short* f1wb  = (unsigned short*)alloc(WB);
    unsigned short* f2wb  = (unsigned short*)alloc(WB);
    float*          zrw   = (float*)alloc(512 * 4);
    unsigned short* combb = (unsigned short*)alloc((size_t)Bn * HI * 2);   // 16.8 MB
    unsigned short* out1  = (unsigned short*)alloc((size_t)Bn * HI * 2);   // 16.8 MB

    size_t fixedB = (size_t)(w - (char*)d_ws);
    int chunk = 32;
    while (chunk > 1 &&
           fixedB + 4ull * (size_t)chunk * Cn * HI * 2 + 4096 > ws_size)
        chunk >>= 1;
    const size_t CB = (size_t)chunk * Cn * HI * 2;
    unsigned short* xst   = (unsigned short*)alloc(CB);   // reused for tz
    unsigned short* tpact = (unsigned short*)alloc(CB);
    unsigned short* tpb   = (unsigned short*)alloc(CB);
    unsigned short* tzin  = (unsigned short*)alloc(CB);
    unsigned short* tzb   = xst;

    prep_wpe_bf<<<512 * 512 / 256, 256, 0, stream>>>(Wp, Wpd, Wpeb);
    conv_bf<<<1024, 256, 0, stream>>>(plw, plwb);
    conv_bf<<<1024, 256, 0, stream>>>(zlw, zlwb);
    conv_bf<<<1024, 256, 0, stream>>>(f1w, f1wb);
    conv_bf<<<1024, 256, 0, stream>>>(f2w, f2wb);
    rowsum<<<512, 64, 0, stream>>>(Wzp, zrw);

    for (int b0 = 0; b0 < Bn; b0 += chunk) {
        const int nc = chunk * Cn;
        const float* inp_c = input + (size_t)b0 * Cn * HI;

        // xst = bf16(x^T * act(mask)/5000)
        transpose_mask<<<dim3(8, 8, nc), 256, 0, stream>>>(inp_c, p_mask, xst);
        // G1: tpact[bc] = act(Wpe @ xst[bc]^T)  — PCOL (xst streamed) + TRI
        mfma_gemm<0, true, true><<<nc * 16, 256, 0, stream>>>(
            Wpeb, xst, nullptr, nullptr, tpact, nullptr, nullptr, HI, HI);
        // G2: tp = act(tpact @ plw^T + plb); tzin = act(zrow*tp)
        mfma_gemm<1, false, false><<<nc * 16, 256, 0, stream>>>(
            tpact, plwb, plb, zrw, tpb, tzin, nullptr, 0, 0);
        // G3: tz = act(tzin @ zlw^T + zlb)
        mfma_gemm<2, false, false><<<nc * 16, 256, 0, stream>>>(
            tzin, zlwb, zlb, nullptr, tzb, nullptr, nullptr, 0, 0);
        // comb = x0/5000 + sum_c tp + sum_c tz
        reduce_both<<<chunk * 256, 256, 0, stream>>>(
            tpb, tzb, inp_c, combb + (size_t)b0 * HI);
    }

    // fc1: out1 = relu(combb @ f1w^T + f1b)
    mfma_gemm<3, false, false><<<512, 256, 0, stream>>>(
        combb, f1wb, f1b, nullptr, out1, nullptr, nullptr, 0, 0);
    // fc2: out = out1 @ f2w^T + f2b   (fp32)
    mfma_gemm<4, false, false><<<512, 256, 0, stream>>>(
        out1, f2wb, f2b, nullptr, nullptr, nullptr, (float*)d_out, 0, 0);
}

// Round 18
// 489.526 us; speedup vs baseline: 1.3234x; 1.3234x over previous
//
#include <hip/hip_runtime.h>

namespace {

constexpr int Bn = 32, Cn = 8, Hn = 512, In = 512;
constexpr size_t HI = (size_t)Hn * In;     // 262144
constexpr float SC = 1.0f / 5000.0f;

using s16x8 = __attribute__((ext_vector_type(8))) short;
using f32x4 = __attribute__((ext_vector_type(4))) float;

__device__ __forceinline__ float actf(float x) {
    return fminf(1.0f, fmaxf(-1.0f, x));   // hardtanh
}

__device__ __forceinline__ unsigned short f2bf(float f) {   // RNE f32->bf16
    unsigned u = __builtin_bit_cast(unsigned, f);
    u += 0x7FFFu + ((u >> 16) & 1u);
    return (unsigned short)(u >> 16);
}
__device__ __forceinline__ float bf2f(unsigned short h) {
    return __builtin_bit_cast(float, (unsigned)h << 16);
}

__device__ __forceinline__ void async16(const void* g, void* l) {
    __builtin_amdgcn_global_load_lds(
        (const __attribute__((address_space(1))) unsigned*)g,
        (__attribute__((address_space(3))) unsigned*)l, 16, 0, 0);
}

#define CFENCE asm volatile("" ::: "memory")
#define BAR do { CFENCE; __builtin_amdgcn_s_barrier(); CFENCE; } while (0)

// ---------------------------------------------------------------------------
// r18: 8-phase 256x256 template (m201 port). BK=64, 8 waves (512 thr),
// per-wave 128x64 output (acc[8][4]). LDS 128KB: dbuf0/1 x (A 32KB + B 32KB),
// row-major [256 rows][128B], source-XOR swizzle ((t&7)^(row&7))<<4 both
// sides (r15 involution: coalescing preserved, ds_read conflict-free).
// Per K-tile: 4 quadrant phases Q(mh,nh) x full K=64 (16 MFMA each);
// reads: P1 a0-3(8)+b0-1(4), P2 b2-3(4), P3 a4-7(8), P4 none (reuse).
// Region-free: A-half after P3, B-half after P2 -> stage slots:
//   P1: A(j+1)h0->db  P2: A(j+1)h1->db  P3: B(j+2)h0->da  P4: B(j+2)h1->da
//   P5: A(j+2)h0->da  P6: A(j+2)h1->da  P7: B(j+3)h0->db  P8: B(j+3)h1->db
// Counted vmcnt(4) ONLY at P4/P8 ends (2 newest stage-ops = 4 instrs stay in
// flight across the barrier); never drained mid-loop (T4). setprio around
// MFMA clusters (T5; pays only on 8-phase). TRI: nkt=(rt+1)*4.
// EPI 0: G1 bf16(act(acc));  1: G2 dual (tp + act(zrow*tp));  2: G3 act+bias.
// ---------------------------------------------------------------------------
template<int EPI, bool PCOL, bool TRI>
__global__ __launch_bounds__(512, 2) void gemm256_8p(
    const unsigned short* __restrict__ A,
    const unsigned short* __restrict__ Bt,
    const float* __restrict__ bias,
    const float* __restrict__ zrow,
    unsigned short* __restrict__ out0,
    unsigned short* __restrict__ out1,
    size_t sB, size_t sC)
{
    __shared__ __align__(16) char lds[131072];
    char* daA = lds;                 // even K-tiles, A tile [256][128B]
    char* dbA = lds + 32768;         // odd  K-tiles, A
    char* daB = lds + 65536;         // even K-tiles, B
    char* dbB = lds + 98304;         // odd  K-tiles, B

    const int tid = threadIdx.x;
    const int lane = tid & 63, l15 = lane & 15, kq = lane >> 4;
    const int wid = tid >> 6, wm = wid >> 2, wn = wid & 3;

    const int bid = blockIdx.x;
    int rt, ct; size_t zb;
    if (PCOL) {   // G1: p=z (XCD-group), q=(rt,ct); grid = nz*4 (mult of 32)
        const int p = ((bid >> 5) << 3) | (bid & 7);
        const int q = (bid >> 3) & 3;
        zb = (size_t)p; rt = q >> 1; ct = q & 1;
    } else {      // G2/G3: p=row-tile, q=ct; grid = M/256*2 (mult of 16)
        const int p = ((bid >> 4) << 3) | (bid & 7);
        const int q = (bid >> 3) & 1;
        zb = 0; rt = p; ct = q;
    }

    const char* Ab = (const char*)A + (size_t)rt * 256 * 1024;
    const char* Bb = (const char*)(Bt + zb * sB) + (size_t)ct * 256 * 1024;

    const int nkt = TRI ? (rt + 1) * 4 : 8;   // 64-K tiles (even)
    const int nit = nkt >> 1;

    // staging: thread t, load i covers row i*64+(t>>3), 16B group (t&7),
    // source col XOR'd by row&7 (involution; within the row's 128B chunk).
    const int srow8 = tid >> 3;                       // 0..63
    const int csw   = ((tid & 7) ^ (srow8 & 7)) << 4;

    auto stageH = [&](const char* src, int kt, int half, char* dstTile) {
        const char* s = src + ((size_t)half * 128 + srow8) * 1024 + kt * 128 + csw;
        char* d = dstTile + half * 16384 + tid * 16;
        async16(s,             d);
        async16(s + 64 * 1024, d + 8192);
    };

    // ds_read: global K-group G=kk*4+kq lives at LDS group G^(row&7); row&7=l15&7
    const int kx0 = ((kq    ) ^ (l15 & 7)) << 4;
    const int kx1 = ((kq + 4) ^ (l15 & 7)) << 4;

    auto rdA4 = [&](const char* tile, int mlo, s16x8 a[2][4]) {
        #pragma unroll
        for (int i = 0; i < 4; ++i) {
            const int row = wm * 128 + (mlo + i) * 16 + l15;
            a[0][i] = *(const s16x8*)(tile + row * 128 + kx0);
            a[1][i] = *(const s16x8*)(tile + row * 128 + kx1);
        }
    };
    auto rdB2 = [&](const char* tile, int nlo, s16x8 b[2][2]) {
        #pragma unroll
        for (int j = 0; j < 2; ++j) {
            const int row = wn * 64 + (nlo + j) * 16 + l15;
            b[0][j] = *(const s16x8*)(tile + row * 128 + kx0);
            b[1][j] = *(const s16x8*)(tile + row * 128 + kx1);
        }
    };

    f32x4 acc[8][4] = {};

    auto QMM = [&](s16x8 a[2][4], s16x8 b[2][2], int mlo, int nlo) {
        __builtin_amdgcn_s_setprio(1);
        #pragma unroll
        for (int kk = 0; kk < 2; ++kk)
            #pragma unroll
            for (int i = 0; i < 4; ++i)
                #pragma unroll
                for (int j = 0; j < 2; ++j)
                    acc[mlo + i][nlo + j] = __builtin_amdgcn_mfma_f32_16x16x32_bf16(
                        a[kk][i], b[kk][j], acc[mlo + i][nlo + j], 0, 0, 0);
        __builtin_amdgcn_s_setprio(0);
    };

    // prologue: K0 complete -> da; B(K1) -> dbB (A(K1) staged in P1/P2)
    stageH(Bb, 0, 0, daB); stageH(Bb, 0, 1, daB);
    stageH(Ab, 0, 0, daA); stageH(Ab, 0, 1, daA);
    stageH(Bb, 1, 0, dbB); stageH(Bb, 1, 1, dbB);
    asm volatile("s_waitcnt vmcnt(4)" ::: "memory");   // K0's 8 loads landed
    BAR;

    #pragma unroll 1
    for (int t = 0; t < nit; ++t) {
        const int j = 2 * t;
        const bool more = (t + 1 < nit);
        s16x8 a03[2][4], a47[2][4], b01[2][2], b23[2][2];

        // ======== K-tile j (dbuf0) ========
        // P1: Q(m0-3, n0-1)
        rdA4(daA, 0, a03); rdB2(daB, 0, b01);
        stageH(Ab, j + 1, 0, dbA);
        BAR; QMM(a03, b01, 0, 0); BAR;
        // P2: Q(m0-3, n2-3)
        rdB2(daB, 2, b23);
        stageH(Ab, j + 1, 1, dbA);
        BAR; QMM(a03, b23, 0, 2); BAR;
        // P3: Q(m4-7, n2-3)   (daB free after P2)
        rdA4(daA, 4, a47);
        if (more) stageH(Bb, j + 2, 0, daB);
        BAR; QMM(a47, b23, 4, 2); BAR;
        // P4: Q(m4-7, n0-1)
        if (more) stageH(Bb, j + 2, 1, daB);
        BAR; QMM(a47, b01, 4, 0);
        if (more) asm volatile("s_waitcnt vmcnt(4)" ::: "memory"); // K(j+1) ready
        else      asm volatile("s_waitcnt vmcnt(0)" ::: "memory");
        BAR;

        // ======== K-tile j+1 (dbuf1) ========
        // P5: Q(m0-3, n0-1)   (daA free after P3)
        rdA4(dbA, 0, a03); rdB2(dbB, 0, b01);
        if (more) stageH(Ab, j + 2, 0, daA);
        BAR; QMM(a03, b01, 0, 0); BAR;
        // P6: Q(m0-3, n2-3)
        rdB2(dbB, 2, b23);
        if (more) stageH(Ab, j + 2, 1, daA);
        BAR; QMM(a03, b23, 0, 2); BAR;
        // P7: Q(m4-7, n2-3)   (dbB free after P6)
        rdA4(dbA, 4, a47);
        if (more) stageH(Bb, j + 3, 0, dbB);
        BAR; QMM(a47, b23, 4, 2); BAR;
        // P8: Q(m4-7, n0-1)
        if (more) stageH(Bb, j + 3, 1, dbB);
        BAR; QMM(a47, b01, 4, 0);
        if (more) { asm volatile("s_waitcnt vmcnt(4)" ::: "memory"); BAR; } // K(j+2) ready
        else BAR;
    }

    // ---- epilogue: C/D map col=lane&15, row=(lane>>4)*4+j ----
    const int rbase = rt * 256 + wm * 128 + kq * 4;
    const int cb    = ct * 256 + wn * 64 + l15;
    #pragma unroll
    for (int mi = 0; mi < 8; ++mi) {
        #pragma unroll
        for (int n = 0; n < 4; ++n) {
            const int c = cb + n * 16;
            const float bs = (EPI == 0) ? 0.0f : bias[c];
            #pragma unroll
            for (int jj = 0; jj < 4; ++jj) {
                const size_t r = (size_t)rbase + mi * 16 + jj;
                const size_t idx = zb * sC + r * 512 + c;
                float v = acc[mi][n][jj];
                if (EPI == 0) {
                    out0[idx] = f2bf(actf(v));
                } else if (EPI == 1) {
                    float tp = actf(v + bs);
                    out0[idx] = f2bf(tp);
                    out1[idx] = f2bf(actf(zrow[r & 511] * tp));
                } else {
                    out0[idx] = f2bf(actf(v + bs));
                }
            }
        }
    }
}

// ---------------------------------------------------------------------------
// r16 128x128 kernel (kept for fc1/fc2: EPI 3 = relu+bias bf16, 4 = fp32+bias)
// ---------------------------------------------------------------------------
template<int EPI>
__global__ __launch_bounds__(256, 3) void mfma_gemm128(
    const unsigned short* __restrict__ A,
    const unsigned short* __restrict__ Bt,
    const float* __restrict__ bias,
    unsigned short* __restrict__ out0,
    float* __restrict__ outf)
{
    __shared__ __align__(16) char lds[2][16384];

    const int tid  = threadIdx.x;
    const int wid  = tid >> 6, lane = tid & 63;
    const int wr   = wid >> 1, wc = wid & 1;
    const int l15  = lane & 15, kq = lane >> 4;

    const int bid = blockIdx.x;
    const int p = ((bid >> 5) << 3) | (bid & 7);
    const int q = (bid >> 3) & 3;
    const int rt = p, ct = q;

    const char* Ab = (const char*)A + (size_t)rt * 131072;
    const char* Bb = (const char*)Bt + (size_t)ct * 131072;

    f32x4 acc[4][4] = {};

    const int o0  = tid * 16;
    const int r0s = o0 >> 6;
    const int c0s = o0 & 63;
    const int csw = c0s ^ (((r0s >> 1) & 3) << 4);

    auto stage = [&](char* buf, int k0b) {
        async16(Ab + (size_t)r0s * 1024 + k0b + csw,        buf + wid * 1024);
        async16(Ab + (size_t)(64 + r0s) * 1024 + k0b + csw, buf + 4096 + wid * 1024);
        async16(Bb + (size_t)r0s * 1024 + k0b + csw,        buf + 8192 + wid * 1024);
        async16(Bb + (size_t)(64 + r0s) * 1024 + k0b + csw, buf + 12288 + wid * 1024);
    };
    auto compute = [&](const char* buf) {
        s16x8 a[4], b[4];
        const int kx = kq * 16 ^ (((l15 >> 1) & 3) << 4);
        const int ar = wr * 64 + l15;
        const int br = wc * 64 + l15;
        #pragma unroll
        for (int m = 0; m < 4; ++m)
            a[m] = *(const s16x8*)(buf + (size_t)(ar + m * 16) * 64 + kx);
        #pragma unroll
        for (int n = 0; n < 4; ++n)
            b[n] = *(const s16x8*)(buf + 8192 + (size_t)(br + n * 16) * 64 + kx);
        #pragma unroll
        for (int m = 0; m < 4; ++m)
            #pragma unroll
            for (int n = 0; n < 4; ++n)
                acc[m][n] = __builtin_amdgcn_mfma_f32_16x16x32_bf16(a[m], b[n], acc[m][n], 0, 0, 0);
    };

    stage(lds[0], 0);
    stage(lds[1], 64);

    #pragma unroll 1
    for (int ks = 0; ks < 16; ks += 2) {
        const bool more = (ks + 2 < 16);
        asm volatile("s_waitcnt vmcnt(4)" ::: "memory");
        BAR;
        compute(lds[0]);
        BAR;
        if (more) stage(lds[0], (ks + 2) * 64);
        if (more) asm volatile("s_waitcnt vmcnt(4)" ::: "memory");
        else      asm volatile("s_waitcnt vmcnt(0)" ::: "memory");
        BAR;
        compute(lds[1]);
        BAR;
        if (more) stage(lds[1], (ks + 3) * 64);
    }

    const int cb = ct * 128 + wc * 64 + l15;
    const int rb = rt * 128 + wr * 64 + (kq << 2);
    #pragma unroll
    for (int m = 0; m < 4; ++m)
        #pragma unroll
        for (int n = 0; n < 4; ++n) {
            const int c = cb + n * 16;
            #pragma unroll
            for (int j = 0; j < 4; ++j) {
                const int r = rb + m * 16 + j;
                const size_t idx = (size_t)r * 512 + c;
                float v = acc[m][n][j] + bias[c];
                if (EPI == 3) out0[idx] = f2bf(fmaxf(v, 0.0f));
                else          outf[idx] = v;
            }
        }
}

// comb[b] = bf16( x0[b]/5000 + sum_c tp[b,c] + sum_c tz[b,c] )
__global__ __launch_bounds__(256) void reduce_both(
    const unsigned short* __restrict__ tp,
    const unsigned short* __restrict__ tz,
    const float* __restrict__ x0,
    unsigned short* __restrict__ comb)
{
    size_t idx = (size_t)blockIdx.x * 256 + threadIdx.x;
    size_t b = idx >> 16;
    size_t p = (idx & 65535) * 4;
    float4 xv = *(const float4*)&x0[(b * Cn) * HI + p];
    float s0 = xv.x * SC, s1 = xv.y * SC, s2 = xv.z * SC, s3 = xv.w * SC;
    #pragma unroll
    for (int c = 0; c < Cn; ++c) {
        size_t q = (b * Cn + c) * HI + p;
        ushort4 a = *(const ushort4*)&tp[q];
        ushort4 d = *(const ushort4*)&tz[q];
        s0 += bf2f(a.x) + bf2f(d.x);
        s1 += bf2f(a.y) + bf2f(d.y);
        s2 += bf2f(a.z) + bf2f(d.z);
        s3 += bf2f(a.w) + bf2f(d.w);
    }
    ushort4 o;
    o.x = f2bf(s0); o.y = f2bf(s1); o.z = f2bf(s2); o.w = f2bf(s3);
    *(ushort4*)&comb[b * HI + p] = o;
}

// xst[bc][i][k] = bf16( x[bc][k][i] * act(mask[k][i]) / 5000 )
__global__ __launch_bounds__(256) void transpose_mask(
    const float* __restrict__ x, const float* __restrict__ mask,
    unsigned short* __restrict__ xst)
{
    __shared__ float t[64][65];
    const int bc = blockIdx.z;
    const int i0 = blockIdx.x * 64, k0 = blockIdx.y * 64;
    const int r4 = threadIdx.x >> 6, cc = threadIdx.x & 63;
    const float* xp = x + (size_t)bc * HI;
    #pragma unroll
    for (int it = 0; it < 16; ++it) {
        int kl = it * 4 + r4;
        size_t g = (size_t)(k0 + kl) * In + i0 + cc;
        t[kl][cc] = xp[g] * (actf(mask[g]) * SC);
    }
    __syncthreads();
    unsigned short* op = xst + (size_t)bc * HI;
    #pragma unroll
    for (int it = 0; it < 16; ++it) {
        int il = it * 4 + r4;
        op[(size_t)(i0 + il) * Hn + k0 + cc] = f2bf(t[cc][il]);
    }
}

__global__ __launch_bounds__(256) void prep_wpe_bf(
    const float* __restrict__ Wp, const float* __restrict__ Wpd,
    unsigned short* __restrict__ o)
{
    int idx = blockIdx.x * 256 + threadIdx.x;
    int i = idx >> 9, j = idx & 511;
    o[idx] = f2bf(Wp[idx] + (i == j ? Wpd[i] : 0.0f));
}

__global__ __launch_bounds__(256) void conv_bf(
    const float* __restrict__ s, unsigned short* __restrict__ o)
{
    int idx = blockIdx.x * 256 + threadIdx.x;
    o[idx] = f2bf(s[idx]);
}

__global__ __launch_bounds__(64) void rowsum(
    const float* __restrict__ W, float* __restrict__ zr)
{
    int h = blockIdx.x, l = threadIdx.x;
    float s = 0.0f;
    for (int k = l; k < Hn; k += 64) s += W[h * Hn + k];
    #pragma unroll
    for (int off = 32; off; off >>= 1) s += __shfl_down(s, off, 64);
    if (!l) zr[h] = s;
}

} // namespace

extern "C" void kernel_launch(void* const* d_in, const int* in_sizes, int n_in,
                              void* d_out, int out_size, void* d_ws, size_t ws_size,
                              hipStream_t stream)
{
    const float* input  = (const float*)d_in[0];
    const float* p_mask = (const float*)d_in[1];
    const float* Wp     = (const float*)d_in[2];
    const float* Wpd    = (const float*)d_in[3];
    const float* Wzp    = (const float*)d_in[4];
    const float* plw    = (const float*)d_in[5];
    const float* plb    = (const float*)d_in[6];
    const float* zlw    = (const float*)d_in[7];
    const float* zlb    = (const float*)d_in[8];
    const float* f1w    = (const float*)d_in[9];
    const float* f1b    = (const float*)d_in[10];
    const float* f2w    = (const float*)d_in[11];
    const float* f2b    = (const float*)d_in[12];

    constexpr size_t WB = 512 * 512 * 2;   // one bf16 weight matrix
    char* w = (char*)d_ws;
    auto alloc = [&](size_t bytes) { char* p = w; w += (bytes + 255) & ~255ull; return p; };

    unsigned short* Wpeb  = (unsigned short*)alloc(WB);
    unsigned short* plwb  = (unsigned short*)alloc(WB);
    unsigned short* zlwb  = (unsigned short*)alloc(WB);
    unsigned short* f1wb  = (unsigned short*)alloc(WB);
    unsigned short* f2wb  = (unsigned short*)alloc(WB);
    float*          zrw   = (float*)alloc(512 * 4);
    unsigned short* combb = (unsigned short*)alloc((size_t)Bn * HI * 2);
    unsigned short* out1  = (unsigned short*)alloc((size_t)Bn * HI * 2);

    size_t fixedB = (size_t)(w - (char*)d_ws);
    int chunk = 32;
    while (chunk > 1 &&
           fixedB + 4ull * (size_t)chunk * Cn * HI * 2 + 4096 > ws_size)
        chunk >>= 1;
    const size_t CB = (size_t)chunk * Cn * HI * 2;
    unsigned short* xst   = (unsigned short*)alloc(CB);   // reused for tz
    unsigned short* tpact = (unsigned short*)alloc(CB);
    unsigned short* tpb   = (unsigned short*)alloc(CB);
    unsigned short* tzin  = (unsigned short*)alloc(CB);
    unsigned short* tzb   = xst;

    prep_wpe_bf<<<512 * 512 / 256, 256, 0, stream>>>(Wp, Wpd, Wpeb);
    conv_bf<<<1024, 256, 0, stream>>>(plw, plwb);
    conv_bf<<<1024, 256, 0, stream>>>(zlw, zlwb);
    conv_bf<<<1024, 256, 0, stream>>>(f1w, f1wb);
    conv_bf<<<1024, 256, 0, stream>>>(f2w, f2wb);
    rowsum<<<512, 64, 0, stream>>>(Wzp, zrw);

    for (int b0 = 0; b0 < Bn; b0 += chunk) {
        const int nc = chunk * Cn;
        const float* inp_c = input + (size_t)b0 * Cn * HI;

        // xst = bf16(x^T * act(mask)/5000)
        transpose_mask<<<dim3(8, 8, nc), 256, 0, stream>>>(inp_c, p_mask, xst);
        // G1: tpact[z] = act(Wpe @ xst[z]^T)  — 8-phase 256², PCOL + TRI
        gemm256_8p<0, true, true><<<nc * 4, 512, 0, stream>>>(
            Wpeb, xst, nullptr, nullptr, tpact, nullptr, HI, HI);
        // G2: tp = act(tpact @ plw^T + plb); tzin = act(zrow*tp)
        gemm256_8p<1, false, false><<<nc * 4, 512, 0, stream>>>(
            tpact, plwb, plb, zrw, tpb, tzin, 0, 0);
        // G3: tz = act(tzin @ zlw^T + zlb)
        gemm256_8p<2, false, false><<<nc * 4, 512, 0, stream>>>(
            tzin, zlwb, zlb, nullptr, tzb, nullptr, 0, 0);
        // comb = x0/5000 + sum_c tp + sum_c tz
        reduce_both<<<chunk * 256, 256, 0, stream>>>(
            tpb, tzb, inp_c, combb + (size_t)b0 * HI);
    }

    // fc1: out1 = relu(combb @ f1w^T + f1b)
    mfma_gemm128<3><<<512, 256, 0, stream>>>(combb, f1wb, f1b, out1, nullptr);
    // fc2: out = out1 @ f2w^T + f2b   (fp32)
    mfma_gemm128<4><<<512, 256, 0, stream>>>(out1, f2wb, f2b, nullptr, (float*)d_out);
}